// Round 2
// baseline (1095.926 us; speedup 1.0000x reference)
//
#include <hip/hip_runtime.h>
#include <hip/hip_bf16.h>

using bf16 = __hip_bfloat16;

__device__ __forceinline__ float ldv(const float* p) { return *p; }
__device__ __forceinline__ float ldv(const bf16* p)  { return __bfloat162float(*p); }
__device__ __forceinline__ void  stv(float* p, float v) { *p = v; }
__device__ __forceinline__ void  stv(bf16* p,  float v) { *p = __float2bfloat16(v); }

// Direct 4D conv (VALID, stride 1) + bias + ReLU.
// Thread = (b, ow, ox, oz) with oz lane-fastest -> coalesced loads/stores.
// Each thread computes the full oy-column (SOUT outputs) for all COUT channels.
// `total` = number of valid threads (b < nbatch); extras return early.
template<int CIN, int COUT, int SIN, int K, typename TIN, typename TOUT>
__global__ __launch_bounds__(256)
void conv4d_relu(const TIN* __restrict__ in, const float* __restrict__ w,
                 const float* __restrict__ bias, TOUT* __restrict__ out, int total)
{
    constexpr int SOUT = SIN - K + 1;
    constexpr int K4 = K * K * K * K;
    constexpr int WN = COUT * CIN * K4;

    __shared__ float wl[WN];
    __shared__ float bl[COUT];
    for (int i = threadIdx.x; i < WN; i += 256) wl[i] = w[i];
    if (threadIdx.x < COUT) bl[threadIdx.x] = bias[threadIdx.x];
    __syncthreads();

    const int t  = blockIdx.x * 256 + threadIdx.x;
    if (t >= total) return;
    const int oz = t % SOUT;
    const int ox = (t / SOUT) % SOUT;
    const int ow = (t / (SOUT * SOUT)) % SOUT;
    const int b  = t / (SOUT * SOUT * SOUT);

    float acc[COUT][SOUT];
    #pragma unroll
    for (int co = 0; co < COUT; ++co)
        #pragma unroll
        for (int oy = 0; oy < SOUT; ++oy) acc[co][oy] = 0.f;

    for (int ci = 0; ci < CIN; ++ci)
    for (int dw = 0; dw < K; ++dw)
    for (int dx = 0; dx < K; ++dx) {
        // w-slice for this (ci,dw,dx): [COUT][K(dy)][K(dz)] into registers
        float wreg[COUT][K][K];
        const int wbase = ((ci * K + dw) * K + dx) * K * K;
        #pragma unroll
        for (int co = 0; co < COUT; ++co)
            #pragma unroll
            for (int dy = 0; dy < K; ++dy)
                #pragma unroll
                for (int dz = 0; dz < K; ++dz)
                    wreg[co][dy][dz] = wl[co * (CIN * K4) + wbase + dy * K + dz];

        const TIN* col = in
            + ((((long)(b * CIN + ci) * SIN + (ow + dw)) * SIN + (ox + dx)) * SIN) * (long)SIN
            + oz;

        #pragma unroll
        for (int iy = 0; iy < SIN; ++iy) {
            float r[K];
            #pragma unroll
            for (int dz = 0; dz < K; ++dz) r[dz] = ldv(col + iy * SIN + dz);
            #pragma unroll
            for (int dy = 0; dy < K; ++dy) {
                if (iy - dy >= 0 && iy - dy < SOUT) {   // compile-time per (iy,dy)
                    #pragma unroll
                    for (int co = 0; co < COUT; ++co)
                        #pragma unroll
                        for (int dz = 0; dz < K; ++dz)
                            acc[co][iy - dy] = fmaf(r[dz], wreg[co][dy][dz], acc[co][iy - dy]);
                }
            }
        }
    }

    #pragma unroll
    for (int co = 0; co < COUT; ++co) {
        TOUT* op = out
            + ((((long)(b * COUT + co) * SOUT + ow) * SOUT + ox) * SOUT) * (long)SOUT
            + oz;
        #pragma unroll
        for (int oy = 0; oy < SOUT; ++oy) {
            float v = acc[co][oy] + bl[co];
            stv(op + oy * SOUT, v > 0.f ? v : 0.f);
        }
    }
}

// Fused dense1(1280->33, ReLU) + dense2(33->2) + softmax. One block (1 wave) per batch item.
// Output is fp32 (reference output dtype).
__global__ __launch_bounds__(64)
void dense_head(const float* __restrict__ h, const float* __restrict__ dw1,
                const float* __restrict__ db1, const float* __restrict__ dw2,
                const float* __restrict__ db2, float* __restrict__ out)
{
    __shared__ float hs[1280];
    __shared__ float g[33];
    const int b = blockIdx.x, l = threadIdx.x;

    for (int i = l; i < 1280; i += 64) hs[i] = h[b * 1280 + i];
    __syncthreads();

    for (int j = 0; j < 33; ++j) {
        float a = 0.f;
        for (int k = l; k < 1280; k += 64) a += hs[k] * dw1[j * 1280 + k];
        #pragma unroll
        for (int off = 32; off > 0; off >>= 1) a += __shfl_down(a, off);
        if (l == 0) { float v = a + db1[j]; g[j] = v > 0.f ? v : 0.f; }
    }
    __syncthreads();

    if (l == 0) {
        float l0 = db2[0], l1 = db2[1];
        for (int j = 0; j < 33; ++j) { l0 += g[j] * dw2[j]; l1 += g[j] * dw2[33 + j]; }
        float m = l0 > l1 ? l0 : l1;
        float e0 = expf(l0 - m), e1 = expf(l1 - m);
        float s = e0 + e1;
        out[b * 2 + 0] = e0 / s;
        out[b * 2 + 1] = e1 / s;
    }
}

extern "C" void kernel_launch(void* const* d_in, const int* in_sizes, int n_in,
                              void* d_out, int out_size, void* d_ws, size_t ws_size,
                              hipStream_t stream)
{
    const float* x   = (const float*)d_in[0];
    const float* w1  = (const float*)d_in[1];  const float* b1  = (const float*)d_in[2];
    const float* w2  = (const float*)d_in[3];  const float* b2  = (const float*)d_in[4];
    const float* w3  = (const float*)d_in[5];  const float* b3  = (const float*)d_in[6];
    const float* w4  = (const float*)d_in[7];  const float* b4  = (const float*)d_in[8];
    const float* w5  = (const float*)d_in[9];  const float* b5  = (const float*)d_in[10];
    const float* dw1 = (const float*)d_in[11]; const float* db1 = (const float*)d_in[12];
    const float* dw2 = (const float*)d_in[13]; const float* db2 = (const float*)d_in[14];
    float* outp = (float*)d_out;

    // element counts of full intermediates
    const size_t F1 = 256L * 3 * 15 * 15 * 15 * 15;  // 38,880,000
    const size_t F2 = 256L * 3 * 12 * 12 * 12 * 12;  // 15,925,248
    const size_t F3 = 256L * 4 * 9 * 9 * 9 * 9;      //  6,718,464
    const size_t F4 = 256L * 5 * 6 * 6 * 6 * 6;      //  1,658,880
    const size_t F5 = 256L * 5 * 4 * 4 * 4 * 4;      //    327,680

    char* base = (char*)d_ws;

    auto T1 = [](int nb){ return nb * 15 * 15 * 15; };  // threads per conv1 launch
    auto T2 = [](int nb){ return nb * 12 * 12 * 12; };
    auto T3 = [](int nb){ return nb * 9 * 9 * 9; };
    auto T4 = [](int nb){ return nb * 6 * 6 * 6; };
    auto T5 = [](int nb){ return nb * 4 * 4 * 4; };
    auto GB = [](int th){ return (th + 255) / 256; };

    if (ws_size >= (F1 + F2) * 4) {
        // Tier A: all fp32 (peak 219.2 MB)
        float* h1 = (float*)base;
        float* h2 = (float*)(base + F1 * 4);
        float* h3 = (float*)base;                     // h1 dead by conv3
        float* h4 = (float*)(base + F3 * 4);
        float* h5 = (float*)(base + (F3 + F4) * 4);
        conv4d_relu<1, 3, 18, 4, float, float><<<GB(T1(256)), 256, 0, stream>>>(x,  w1, b1, h1, T1(256));
        conv4d_relu<3, 3, 15, 4, float, float><<<GB(T2(256)), 256, 0, stream>>>(h1, w2, b2, h2, T2(256));
        conv4d_relu<3, 4, 12, 4, float, float><<<GB(T3(256)), 256, 0, stream>>>(h2, w3, b3, h3, T3(256));
        conv4d_relu<4, 5, 9,  4, float, float><<<GB(T4(256)), 256, 0, stream>>>(h3, w4, b4, h4, T4(256));
        conv4d_relu<5, 5, 6,  3, float, float><<<GB(T5(256)), 256, 0, stream>>>(h4, w5, b5, h5, T5(256));
        dense_head<<<256, 64, 0, stream>>>(h5, dw1, db1, dw2, db2, outp);
    } else if (ws_size >= F1 * 2 + F2 * 2) {
        // Tier B: h1,h2 bf16 (peak 109.6 MB); h3..h5 fp32 overlaid on h1's region
        bf16*  h1 = (bf16*)base;
        bf16*  h2 = (bf16*)(base + F1 * 2);
        float* h3 = (float*)base;
        float* h4 = (float*)(base + F3 * 4);
        float* h5 = (float*)(base + (F3 + F4) * 4);
        conv4d_relu<1, 3, 18, 4, float, bf16 ><<<GB(T1(256)), 256, 0, stream>>>(x,  w1, b1, h1, T1(256));
        conv4d_relu<3, 3, 15, 4, bf16,  bf16 ><<<GB(T2(256)), 256, 0, stream>>>(h1, w2, b2, h2, T2(256));
        conv4d_relu<3, 4, 12, 4, bf16,  float><<<GB(T3(256)), 256, 0, stream>>>(h2, w3, b3, h3, T3(256));
        conv4d_relu<4, 5, 9,  4, float, float><<<GB(T4(256)), 256, 0, stream>>>(h3, w4, b4, h4, T4(256));
        conv4d_relu<5, 5, 6,  3, float, float><<<GB(T5(256)), 256, 0, stream>>>(h4, w5, b5, h5, T5(256));
        dense_head<<<256, 64, 0, stream>>>(h5, dw1, db1, dw2, db2, outp);
    } else {
        // Tier D: batch-chunked fp32, 8 chunks of 32 (peak ~28.8 MB)
        const int BC = 32, NCHUNK = 8;
        const size_t C1 = (size_t)BC * 3 * 15 * 15 * 15 * 15;  // 4,860,000
        float* h5 = (float*)base;                              // full [256,1280]
        float* hA = (float*)(base + F5 * 4);                   // chunk h1 / h3
        float* hB = (float*)(base + F5 * 4 + C1 * 4);          // chunk h2 / h4
        for (int c = 0; c < NCHUNK; ++c) {
            const float* xc = x + (size_t)c * BC * 18L * 18 * 18 * 18;
            float* h5c = h5 + (size_t)c * BC * 1280;
            conv4d_relu<1, 3, 18, 4, float, float><<<GB(T1(BC)), 256, 0, stream>>>(xc, w1, b1, hA, T1(BC));
            conv4d_relu<3, 3, 15, 4, float, float><<<GB(T2(BC)), 256, 0, stream>>>(hA, w2, b2, hB, T2(BC));
            conv4d_relu<3, 4, 12, 4, float, float><<<GB(T3(BC)), 256, 0, stream>>>(hB, w3, b3, hA, T3(BC));
            conv4d_relu<4, 5, 9,  4, float, float><<<GB(T4(BC)), 256, 0, stream>>>(hA, w4, b4, hB, T4(BC));
            conv4d_relu<5, 5, 6,  3, float, float><<<GB(T5(BC)), 256, 0, stream>>>(hB, w5, b5, h5c, T5(BC));
        }
        dense_head<<<256, 64, 0, stream>>>(h5, dw1, db1, dw2, db2, outp);
    }
}

// Round 3
// 1006.902 us; speedup vs baseline: 1.0884x; 1.0884x over previous
//
#include <hip/hip_runtime.h>
#include <hip/hip_bf16.h>

using bf16 = __hip_bfloat16;

__device__ __forceinline__ float ldv(const float* p) { return *p; }
__device__ __forceinline__ float ldv(const bf16* p)  { return __bfloat162float(*p); }
__device__ __forceinline__ void  stv(float* p, float v) { *p = v; }
__device__ __forceinline__ void  stv(bf16* p,  float v) { *p = __float2bfloat16(v); }

// Direct 4D conv (VALID, stride 1) + bias + ReLU.
// Thread = (b, ow, ox, oz), oz lane-fastest -> coalesced loads/stores.
// Each thread computes the full oy-column (SOUT outputs) for all COUT channels.
// Weights are read with wave-UNIFORM indices straight from global memory so the
// compiler scalarizes them into SGPRs (s_load) and feeds v_fmac_f32 acc, s, v.
// No LDS, no __syncthreads.
template<int CIN, int COUT, int SIN, int K, typename TIN, typename TOUT>
__global__ __launch_bounds__(256)
void conv4d_relu(const TIN* __restrict__ in, const float* __restrict__ w,
                 const float* __restrict__ bias, TOUT* __restrict__ out, int total)
{
    constexpr int SOUT = SIN - K + 1;
    constexpr int K4 = K * K * K * K;

    const int t = blockIdx.x * 256 + threadIdx.x;
    if (t >= total) return;
    const int oz = t % SOUT;
    const int ox = (t / SOUT) % SOUT;
    const int ow = (t / (SOUT * SOUT)) % SOUT;
    const int b  = t / (SOUT * SOUT * SOUT);

    float acc[COUT][SOUT];
    #pragma unroll
    for (int co = 0; co < COUT; ++co)
        #pragma unroll
        for (int oy = 0; oy < SOUT; ++oy) acc[co][oy] = 0.f;

    for (int ci = 0; ci < CIN; ++ci)
    for (int dw = 0; dw < K; ++dw)
    for (int dx = 0; dx < K; ++dx) {
        // Wave-uniform weight slice [COUT][K(dy)][K(dz)] -> SGPRs via s_load.
        float wv[COUT][K][K];
        const int wbase = ((ci * K + dw) * K + dx) * K * K;
        #pragma unroll
        for (int co = 0; co < COUT; ++co)
            #pragma unroll
            for (int dy = 0; dy < K; ++dy)
                #pragma unroll
                for (int dz = 0; dz < K; ++dz)
                    wv[co][dy][dz] = w[co * (CIN * K4) + wbase + dy * K + dz];

        const TIN* col = in
            + ((((long)(b * CIN + ci) * SIN + (ow + dw)) * SIN + (ox + dx)) * SIN) * (long)SIN
            + oz;

        #pragma unroll
        for (int iy = 0; iy < SIN; ++iy) {
            float r[K];
            #pragma unroll
            for (int dz = 0; dz < K; ++dz) r[dz] = ldv(col + iy * SIN + dz);
            #pragma unroll
            for (int dy = 0; dy < K; ++dy) {
                if (iy - dy >= 0 && iy - dy < SOUT) {   // compile-time per (iy,dy)
                    #pragma unroll
                    for (int co = 0; co < COUT; ++co)
                        #pragma unroll
                        for (int dz = 0; dz < K; ++dz)
                            acc[co][iy - dy] = fmaf(r[dz], wv[co][dy][dz], acc[co][iy - dy]);
                }
            }
        }
    }

    #pragma unroll
    for (int co = 0; co < COUT; ++co) {
        const float bb = bias[co];          // uniform -> SGPR
        TOUT* op = out
            + ((((long)(b * COUT + co) * SOUT + ow) * SOUT + ox) * SOUT) * (long)SOUT
            + oz;
        #pragma unroll
        for (int oy = 0; oy < SOUT; ++oy) {
            float v = acc[co][oy] + bb;
            stv(op + oy * SOUT, v > 0.f ? v : 0.f);
        }
    }
}

// Fused dense1(1280->33, ReLU) + dense2(33->2) + softmax. One block (1 wave) per batch item.
__global__ __launch_bounds__(64)
void dense_head(const float* __restrict__ h, const float* __restrict__ dw1,
                const float* __restrict__ db1, const float* __restrict__ dw2,
                const float* __restrict__ db2, float* __restrict__ out)
{
    __shared__ float hs[1280];
    __shared__ float g[33];
    const int b = blockIdx.x, l = threadIdx.x;

    for (int i = l; i < 1280; i += 64) hs[i] = h[b * 1280 + i];
    __syncthreads();

    for (int j = 0; j < 33; ++j) {
        float a = 0.f;
        for (int k = l; k < 1280; k += 64) a += hs[k] * dw1[j * 1280 + k];
        #pragma unroll
        for (int off = 32; off > 0; off >>= 1) a += __shfl_down(a, off);
        if (l == 0) { float v = a + db1[j]; g[j] = v > 0.f ? v : 0.f; }
    }
    __syncthreads();

    if (l == 0) {
        float l0 = db2[0], l1 = db2[1];
        for (int j = 0; j < 33; ++j) { l0 += g[j] * dw2[j]; l1 += g[j] * dw2[33 + j]; }
        float m = l0 > l1 ? l0 : l1;
        float e0 = expf(l0 - m), e1 = expf(l1 - m);
        float s = e0 + e1;
        out[b * 2 + 0] = e0 / s;
        out[b * 2 + 1] = e1 / s;
    }
}

extern "C" void kernel_launch(void* const* d_in, const int* in_sizes, int n_in,
                              void* d_out, int out_size, void* d_ws, size_t ws_size,
                              hipStream_t stream)
{
    const float* x   = (const float*)d_in[0];
    const float* w1  = (const float*)d_in[1];  const float* b1  = (const float*)d_in[2];
    const float* w2  = (const float*)d_in[3];  const float* b2  = (const float*)d_in[4];
    const float* w3  = (const float*)d_in[5];  const float* b3  = (const float*)d_in[6];
    const float* w4  = (const float*)d_in[7];  const float* b4  = (const float*)d_in[8];
    const float* w5  = (const float*)d_in[9];  const float* b5  = (const float*)d_in[10];
    const float* dw1 = (const float*)d_in[11]; const float* db1 = (const float*)d_in[12];
    const float* dw2 = (const float*)d_in[13]; const float* db2 = (const float*)d_in[14];
    float* outp = (float*)d_out;

    // element counts of full intermediates
    const size_t F1 = 256L * 3 * 15 * 15 * 15 * 15;  // 38,880,000
    const size_t F2 = 256L * 3 * 12 * 12 * 12 * 12;  // 15,925,248
    const size_t F3 = 256L * 4 * 9 * 9 * 9 * 9;      //  6,718,464
    const size_t F4 = 256L * 5 * 6 * 6 * 6 * 6;      //  1,658,880
    const size_t F5 = 256L * 5 * 4 * 4 * 4 * 4;      //    327,680

    char* base = (char*)d_ws;

    auto T1 = [](int nb){ return nb * 15 * 15 * 15; };
    auto T2 = [](int nb){ return nb * 12 * 12 * 12; };
    auto T3 = [](int nb){ return nb * 9 * 9 * 9; };
    auto T4 = [](int nb){ return nb * 6 * 6 * 6; };
    auto T5 = [](int nb){ return nb * 4 * 4 * 4; };
    auto GB = [](int th){ return (th + 255) / 256; };

    if (ws_size >= (F1 + F2) * 4) {
        // Tier A: all fp32 (peak 219.2 MB)
        float* h1 = (float*)base;
        float* h2 = (float*)(base + F1 * 4);
        float* h3 = (float*)base;                     // h1 dead by conv3
        float* h4 = (float*)(base + F3 * 4);
        float* h5 = (float*)(base + (F3 + F4) * 4);
        conv4d_relu<1, 3, 18, 4, float, float><<<GB(T1(256)), 256, 0, stream>>>(x,  w1, b1, h1, T1(256));
        conv4d_relu<3, 3, 15, 4, float, float><<<GB(T2(256)), 256, 0, stream>>>(h1, w2, b2, h2, T2(256));
        conv4d_relu<3, 4, 12, 4, float, float><<<GB(T3(256)), 256, 0, stream>>>(h2, w3, b3, h3, T3(256));
        conv4d_relu<4, 5, 9,  4, float, float><<<GB(T4(256)), 256, 0, stream>>>(h3, w4, b4, h4, T4(256));
        conv4d_relu<5, 5, 6,  3, float, float><<<GB(T5(256)), 256, 0, stream>>>(h4, w5, b5, h5, T5(256));
        dense_head<<<256, 64, 0, stream>>>(h5, dw1, db1, dw2, db2, outp);
    } else if (ws_size >= F1 * 2 + F2 * 2) {
        // Tier B: h1,h2 bf16 (peak 109.6 MB); h3..h5 fp32 overlaid on h1's region
        bf16*  h1 = (bf16*)base;
        bf16*  h2 = (bf16*)(base + F1 * 2);
        float* h3 = (float*)base;
        float* h4 = (float*)(base + F3 * 4);
        float* h5 = (float*)(base + (F3 + F4) * 4);
        conv4d_relu<1, 3, 18, 4, float, bf16 ><<<GB(T1(256)), 256, 0, stream>>>(x,  w1, b1, h1, T1(256));
        conv4d_relu<3, 3, 15, 4, bf16,  bf16 ><<<GB(T2(256)), 256, 0, stream>>>(h1, w2, b2, h2, T2(256));
        conv4d_relu<3, 4, 12, 4, bf16,  float><<<GB(T3(256)), 256, 0, stream>>>(h2, w3, b3, h3, T3(256));
        conv4d_relu<4, 5, 9,  4, float, float><<<GB(T4(256)), 256, 0, stream>>>(h3, w4, b4, h4, T4(256));
        conv4d_relu<5, 5, 6,  3, float, float><<<GB(T5(256)), 256, 0, stream>>>(h4, w5, b5, h5, T5(256));
        dense_head<<<256, 64, 0, stream>>>(h5, dw1, db1, dw2, db2, outp);
    } else {
        // Tier D: batch-chunked fp32, 8 chunks of 32 (peak ~28.8 MB)
        const int BC = 32, NCHUNK = 8;
        const size_t C1 = (size_t)BC * 3 * 15 * 15 * 15 * 15;  // 4,860,000
        float* h5 = (float*)base;                              // full [256,1280]
        float* hA = (float*)(base + F5 * 4);
        float* hB = (float*)(base + F5 * 4 + C1 * 4);
        for (int c = 0; c < NCHUNK; ++c) {
            const float* xc = x + (size_t)c * BC * 18L * 18 * 18 * 18;
            float* h5c = h5 + (size_t)c * BC * 1280;
            conv4d_relu<1, 3, 18, 4, float, float><<<GB(T1(BC)), 256, 0, stream>>>(xc, w1, b1, hA, T1(BC));
            conv4d_relu<3, 3, 15, 4, float, float><<<GB(T2(BC)), 256, 0, stream>>>(hA, w2, b2, hB, T2(BC));
            conv4d_relu<3, 4, 12, 4, float, float><<<GB(T3(BC)), 256, 0, stream>>>(hB, w3, b3, hA, T3(BC));
            conv4d_relu<4, 5, 9,  4, float, float><<<GB(T4(BC)), 256, 0, stream>>>(hA, w4, b4, hB, T4(BC));
            conv4d_relu<5, 5, 6,  3, float, float><<<GB(T5(BC)), 256, 0, stream>>>(hB, w5, b5, h5c, T5(BC));
        }
        dense_head<<<256, 64, 0, stream>>>(h5, dw1, db1, dw2, db2, outp);
    }
}